// Round 6
// baseline (3325.361 us; speedup 1.0000x reference)
//
#include <hip/hip_runtime.h>
#include <stdint.h>
#include <stddef.h>

#define B_ 256
#define L_ 151
#define D_ 256
#define H_ 8
#define DH_ 32
#define FF_ 2048
#define NL_ 6
#define M_ (B_ * L_)      // 38656 = 302 * 128

typedef unsigned short ushort_t;
typedef __bf16 bf16x8 __attribute__((ext_vector_type(8)));
typedef float f32x4 __attribute__((ext_vector_type(4)));
typedef unsigned short us8 __attribute__((ext_vector_type(8)));

__device__ __forceinline__ float bf2f(ushort_t u) {
    union { unsigned int i; float f; } v;
    v.i = ((unsigned int)u) << 16;
    return v.f;
}
__device__ __forceinline__ ushort_t f2bf(float f) {
    union { float f; unsigned int i; } v;
    v.f = f;
    unsigned int x = v.i;
    return (ushort_t)((x + 0x7fffu + ((x >> 16) & 1u)) >> 16);
}

__device__ __forceinline__ void gld_lds16(const ushort_t* g, ushort_t* l) {
    __builtin_amdgcn_global_load_lds(
        (const __attribute__((address_space(1))) void*)g,
        (__attribute__((address_space(3))) void*)l,
        16, 0, 0);
}

// ---------------------------------------------------------------------------
// Input dtype detection (flag: 0 = bf16 inputs, 1 = fp32 inputs).
// ---------------------------------------------------------------------------
__global__ __launch_bounds__(256)
void detect_kernel(const unsigned int* __restrict__ w, int* __restrict__ flag)
{
    __shared__ int sh[256];
    int tid = threadIdx.x;
    int cnt = 0;
    for (int i = tid; i < 1024; i += 256) {
        unsigned int x = w[i];
        int e = (x >> 7) & 0xFF;
        cnt += (e >= 110 && e <= 140) ? 1 : 0;
    }
    sh[tid] = cnt;
    __syncthreads();
    for (int s = 128; s > 0; s >>= 1) {
        if (tid < s) sh[tid] += sh[tid + s];
        __syncthreads();
    }
    if (tid == 0) *flag = (sh[0] > 512) ? 0 : 1;
}

// ---------------------------------------------------------------------------
// Convert ALL weights/biases to bf16 in one launch (compile-time segment map).
// ---------------------------------------------------------------------------
struct WPtrs { const void* p[12]; };

#define WTOT 7890432

__global__ __launch_bounds__(256)
void cvt_all_kernel(WPtrs w, const int* __restrict__ flag, ushort_t* __restrict__ out)
{
    size_t i = (size_t)blockIdx.x * 256 + threadIdx.x;
    if (i >= WTOT) return;
    int a; size_t base;
    if      (i < 1179648) { a = 0;  base = 0; }
    else if (i < 1184256) { a = 1;  base = 1179648; }
    else if (i < 1577472) { a = 2;  base = 1184256; }
    else if (i < 1579008) { a = 3;  base = 1577472; }
    else if (i < 4724736) { a = 4;  base = 1579008; }
    else if (i < 4737024) { a = 5;  base = 4724736; }
    else if (i < 7882752) { a = 6;  base = 4737024; }
    else if (i < 7884288) { a = 7;  base = 7882752; }
    else if (i < 7885824) { a = 8;  base = 7884288; }
    else if (i < 7887360) { a = 9;  base = 7885824; }
    else if (i < 7888896) { a = 10; base = 7887360; }
    else                  { a = 11; base = 7888896; }
    size_t j = i - base;
    if (*flag) out[i] = f2bf(((const float*)w.p[a])[j]);
    else       out[i] = ((const ushort_t*)w.p[a])[j];
}

// src -> fp32 residual stream + bf16 GEMM copy.
__global__ __launch_bounds__(256)
void cvt_src_kernel(const void* __restrict__ in, const int* __restrict__ flag,
                    float* __restrict__ xf, ushort_t* __restrict__ xb)
{
    size_t i = (size_t)blockIdx.x * 256 + threadIdx.x;
    float v = (*flag) ? ((const float*)in)[i] : bf2f(((const ushort_t*)in)[i]);
    xf[i] = v;
    xb[i] = f2bf(v);
}

// ---------------------------------------------------------------------------
// GEMM (m97): 128x128 tile, 4 waves, BK=64, global_load_lds staging.
// mode 0: bf16 store; mode 2: fp32 Out[i] += v (residual fusion).
// Used for QKV projection and attention out-projection (K=256).
// ---------------------------------------------------------------------------
__global__ __launch_bounds__(256, 2)
void gemm_bt(const ushort_t* __restrict__ A, const ushort_t* __restrict__ Bw,
             const ushort_t* __restrict__ bias, void* __restrict__ Out,
             int N, int K, int lda, int mode)
{
    alignas(16) __shared__ ushort_t lsA[128 * 64];
    alignas(16) __shared__ ushort_t lsB[128 * 64];

    const int tid  = threadIdx.x;
    const int wave = tid >> 6;
    const int lane = tid & 63;
    const int row0 = blockIdx.y * 128;
    const int col0 = blockIdx.x * 128;

    const int wr   = (wave >> 1) * 64;
    const int wc   = (wave & 1) * 64;
    const int lm   = lane & 15;
    const int quad = lane >> 4;

    f32x4 acc[4][4];
#pragma unroll
    for (int i = 0; i < 4; ++i)
#pragma unroll
        for (int j = 0; j < 4; ++j)
            acc[i][j] = (f32x4){0.f, 0.f, 0.f, 0.f};

    for (int k0 = 0; k0 < K; k0 += 64) {
        __syncthreads();
#pragma unroll
        for (int it = 0; it < 4; ++it) {
            int c16 = (it * 4 + wave) * 64 + lane;
            int r   = c16 >> 3;
            int kc  = c16 & 7;
            const ushort_t* ga = A  + (size_t)(row0 + r) * lda + k0 + kc * 8;
            const ushort_t* gb = Bw + (size_t)(col0 + r) * K   + k0 + kc * 8;
            gld_lds16(ga, &lsA[(size_t)(it * 4 + wave) * 512]);
            gld_lds16(gb, &lsB[(size_t)(it * 4 + wave) * 512]);
        }
        __syncthreads();

#pragma unroll
        for (int kc = 0; kc < 2; ++kc) {
            bf16x8 af[4], bfr[4];
#pragma unroll
            for (int i = 0; i < 4; ++i) {
                af[i]  = *reinterpret_cast<const bf16x8*>(
                             &lsA[(wr + i * 16 + lm) * 64 + kc * 32 + quad * 8]);
                bfr[i] = *reinterpret_cast<const bf16x8*>(
                             &lsB[(wc + i * 16 + lm) * 64 + kc * 32 + quad * 8]);
            }
#pragma unroll
            for (int i = 0; i < 4; ++i)
#pragma unroll
                for (int j = 0; j < 4; ++j)
                    acc[i][j] = __builtin_amdgcn_mfma_f32_16x16x32_bf16(
                        af[i], bfr[j], acc[i][j], 0, 0, 0);
        }
    }

    float bvals[4];
#pragma unroll
    for (int j = 0; j < 4; ++j)
        bvals[j] = bf2f(bias[col0 + wc + j * 16 + lm]);

#pragma unroll
    for (int i = 0; i < 4; ++i) {
        int mrow = row0 + wr + i * 16 + quad * 4;
#pragma unroll
        for (int j = 0; j < 4; ++j) {
            int ncol = col0 + wc + j * 16 + lm;
#pragma unroll
            for (int r = 0; r < 4; ++r) {
                float v = acc[i][j][r] + bvals[j];
                size_t idx = (size_t)(mrow + r) * N + ncol;
                if (mode == 2) {
                    ((float*)Out)[idx] += v;
                } else {
                    ((ushort_t*)Out)[idx] = f2bf(v);
                }
            }
        }
    }
}

// ---------------------------------------------------------------------------
// Fused FFN: x_f32[128-row strip] += W2 @ relu(W1 @ x + b1) + b2.
// 302 blocks x 512 threads (8 waves). h never touches HBM: per 128-col
// h-chunk, P = relu(x@W1^T+b1) is computed (waves tile 4 row x 2 col), stored
// bf16 in LDS (pad stride 136 -> 2-way banks = free), then FF2 accumulates
// (waves tile 2 row x 4 col). x/W frags read direct from global (L2-hot:
// W1+W2 = 2MB fits per-XCD L2; x strip = 64KB). 512 thr forces VGPR<=256.
// ---------------------------------------------------------------------------
__global__ __launch_bounds__(512)
void ffn_kernel(const ushort_t* __restrict__ xb, const ushort_t* __restrict__ W1,
                const ushort_t* __restrict__ b1, const ushort_t* __restrict__ W2,
                const ushort_t* __restrict__ b2, float* __restrict__ xf)
{
    alignas(16) __shared__ ushort_t Ps[128 * 136];

    const int wave = threadIdx.x >> 6;
    const int lane = threadIdx.x & 63;
    const int lm   = lane & 15;
    const int quad = lane >> 4;
    const int row0 = blockIdx.x * 128;

    const int pr = (wave & 3) * 32;   // P-phase: wave row base (within strip)
    const int pc = (wave >> 2) * 64;  // P-phase: wave col base (within chunk)
    const int fr = (wave & 1) * 64;   // FF2: wave row base
    const int fc = (wave >> 1) * 64;  // FF2: wave col base (output col)

    f32x4 acc[4][4];
#pragma unroll
    for (int i = 0; i < 4; ++i)
#pragma unroll
        for (int j = 0; j < 4; ++j)
            acc[i][j] = (f32x4){0.f, 0.f, 0.f, 0.f};

    for (int c = 0; c < 16; ++c) {
        const int hbase = c * 128;

        // ---- P = relu(x @ W1^T + b1) for this chunk's 128 h-cols ----
        f32x4 p[2][4];
#pragma unroll
        for (int i = 0; i < 2; ++i)
#pragma unroll
            for (int j = 0; j < 4; ++j)
                p[i][j] = (f32x4){0.f, 0.f, 0.f, 0.f};

#pragma unroll
        for (int kk = 0; kk < 8; ++kk) {
            bf16x8 xa[2];
#pragma unroll
            for (int i = 0; i < 2; ++i)
                xa[i] = *(const bf16x8*)(xb + (size_t)(row0 + pr + i * 16 + lm) * 256
                                            + kk * 32 + quad * 8);
#pragma unroll
            for (int j = 0; j < 4; ++j) {
                bf16x8 wb = *(const bf16x8*)(W1 + (size_t)(hbase + pc + j * 16 + lm) * 256
                                                + kk * 32 + quad * 8);
#pragma unroll
                for (int i = 0; i < 2; ++i)
                    p[i][j] = __builtin_amdgcn_mfma_f32_16x16x32_bf16(xa[i], wb, p[i][j], 0, 0, 0);
            }
        }

#pragma unroll
        for (int j = 0; j < 4; ++j) {
            float bv = bf2f(b1[hbase + pc + j * 16 + lm]);
#pragma unroll
            for (int i = 0; i < 2; ++i)
#pragma unroll
                for (int r = 0; r < 4; ++r) {
                    float v = fmaxf(p[i][j][r] + bv, 0.f);
                    Ps[(pr + i * 16 + quad * 4 + r) * 136 + pc + j * 16 + lm] = f2bf(v);
                }
        }
        __syncthreads();   // P complete

        // ---- acc += P @ W2chunk^T ----
#pragma unroll
        for (int k = 0; k < 4; ++k) {
            bf16x8 pa[4];
#pragma unroll
            for (int i = 0; i < 4; ++i)
                pa[i] = *(const bf16x8*)&Ps[(fr + i * 16 + lm) * 136 + k * 32 + quad * 8];
#pragma unroll
            for (int j = 0; j < 4; ++j) {
                bf16x8 w2b = *(const bf16x8*)(W2 + (size_t)(fc + j * 16 + lm) * 2048
                                                 + hbase + k * 32 + quad * 8);
#pragma unroll
                for (int i = 0; i < 4; ++i)
                    acc[i][j] = __builtin_amdgcn_mfma_f32_16x16x32_bf16(pa[i], w2b, acc[i][j], 0, 0, 0);
            }
        }
        __syncthreads();   // P consumed; safe to overwrite next chunk
    }

    // ---- epilogue: x_f32 += acc + b2 ----
    float b2v[4];
#pragma unroll
    for (int j = 0; j < 4; ++j)
        b2v[j] = bf2f(b2[fc + j * 16 + lm]);

#pragma unroll
    for (int i = 0; i < 4; ++i) {
        int mrow = row0 + fr + i * 16 + quad * 4;
#pragma unroll
        for (int j = 0; j < 4; ++j) {
            int ncol = fc + j * 16 + lm;
#pragma unroll
            for (int r = 0; r < 4; ++r)
                xf[(size_t)(mrow + r) * 256 + ncol] += acc[i][j][r] + b2v[j];
        }
    }
}

// ---------------------------------------------------------------------------
// MFMA block-diagonal attention, wave-per-head, zero block barriers.
// ---------------------------------------------------------------------------
__constant__ int c_starts[6] = {0, 50, 67, 84, 101, 151};

__global__ __launch_bounds__(256)
void attn_kernel(ushort_t* __restrict__ qkv)
{
    alignas(16) __shared__ ushort_t Vt[4][32 * 72];  // V^T: [dh][key]
    alignas(16) __shared__ ushort_t Pss[4][16 * 72]; // P strip: [row][key]

    const int b    = blockIdx.x / 5;
    const int blk  = blockIdx.x % 5;
    const int a0   = c_starts[blk];
    const int n    = c_starts[blk + 1] - a0;
    const int wave = threadIdx.x >> 6;
    const int lane = threadIdx.x & 63;
    const int lm   = lane & 15;
    const int quad = lane >> 4;
    const float scale = 0.17677669529663687f;  // 1/sqrt(32)

    const size_t rowbase = (size_t)b * L_ + a0;

    for (int hi = 0; hi < 2; ++hi) {
        const int h = wave + hi * 4;
        const int hoff = h * 32;

#pragma unroll
        for (int it = 0; it < 4; ++it) {
            int gidx = it * 64 + lane;
            int c    = gidx >> 2;
            int dcc  = (gidx & 3) * 8;
            us8 v = *(const us8*)(qkv + (rowbase + c) * 768 + 512 + hoff + dcc);
            if (c >= n) v = (us8){0,0,0,0,0,0,0,0};
#pragma unroll
            for (int j = 0; j < 8; ++j)
                Vt[wave][(dcc + j) * 72 + c] = v[j];
        }

        bf16x8 kb[4];
#pragma unroll
        for (int j = 0; j < 4; ++j)
            kb[j] = *(const bf16x8*)(qkv + (rowbase + 16 * j + lm) * 768 + 256 + hoff + quad * 8);

        bf16x8 vb[2][2];
#pragma unroll
        for (int t = 0; t < 2; ++t)
#pragma unroll
            for (int kc = 0; kc < 2; ++kc)
                vb[t][kc] = *(const bf16x8*)&Vt[wave][(16 * t + lm) * 72 + kc * 32 + quad * 8];

        for (int i = 0; i < 4 && 16 * i < n; ++i) {
            bf16x8 qa = *(const bf16x8*)(qkv + (rowbase + 16 * i + lm) * 768 + hoff + quad * 8);

            f32x4 s[4];
#pragma unroll
            for (int j = 0; j < 4; ++j)
                s[j] = __builtin_amdgcn_mfma_f32_16x16x32_bf16(
                    qa, kb[j], (f32x4){0.f, 0.f, 0.f, 0.f}, 0, 0, 0);

#pragma unroll
            for (int j = 0; j < 4; ++j) {
                bool valid = (16 * j + lm) < n;
#pragma unroll
                for (int r = 0; r < 4; ++r)
                    s[j][r] = valid ? s[j][r] * scale : -1e30f;
            }

            float inv[4];
#pragma unroll
            for (int r = 0; r < 4; ++r) {
                float mx = fmaxf(fmaxf(s[0][r], s[1][r]), fmaxf(s[2][r], s[3][r]));
#pragma unroll
                for (int o2 = 1; o2 < 16; o2 <<= 1) mx = fmaxf(mx, __shfl_xor(mx, o2, 64));
                float sum = 0.f;
#pragma unroll
                for (int j = 0; j < 4; ++j) {
                    float ev = __expf(s[j][r] - mx);
                    s[j][r] = ev;
                    sum += ev;
                }
#pragma unroll
                for (int o2 = 1; o2 < 16; o2 <<= 1) sum += __shfl_xor(sum, o2, 64);
                inv[r] = 1.0f / sum;
            }

#pragma unroll
            for (int j = 0; j < 4; ++j)
#pragma unroll
                for (int r = 0; r < 4; ++r)
                    Pss[wave][(quad * 4 + r) * 72 + 16 * j + lm] = f2bf(s[j][r]);

            bf16x8 pa0 = *(const bf16x8*)&Pss[wave][lm * 72 + quad * 8];
            bf16x8 pa1 = *(const bf16x8*)&Pss[wave][lm * 72 + 32 + quad * 8];

            f32x4 o[2];
#pragma unroll
            for (int t = 0; t < 2; ++t) {
                o[t] = __builtin_amdgcn_mfma_f32_16x16x32_bf16(
                    pa0, vb[t][0], (f32x4){0.f, 0.f, 0.f, 0.f}, 0, 0, 0);
                o[t] = __builtin_amdgcn_mfma_f32_16x16x32_bf16(
                    pa1, vb[t][1], o[t], 0, 0, 0);
            }

#pragma unroll
            for (int r = 0; r < 4; ++r) {
                int m = 16 * i + quad * 4 + r;
                if (m < n) {
#pragma unroll
                    for (int t = 0; t < 2; ++t)
                        qkv[(rowbase + m) * 768 + hoff + 16 * t + lm] =
                            f2bf(o[t][r] * inv[r]);
                }
            }
        }
    }
}

// ---------------------------------------------------------------------------
// LayerNorm over pre-summed x_f32 (residual adds fused into producers).
// ---------------------------------------------------------------------------
__global__ __launch_bounds__(256)
void ln_kernel(float* __restrict__ xf, const ushort_t* __restrict__ s,
               const ushort_t* __restrict__ b, ushort_t* __restrict__ xb_out,
               float* __restrict__ f32_dst, const int* __restrict__ flag,
               int is_final)
{
    const int wave = threadIdx.x >> 6;
    const int lane = threadIdx.x & 63;
    const int row  = blockIdx.x * 4 + wave;
    const size_t off = (size_t)row * D_ + lane * 4;

    float4 xv = *(const float4*)(xf + off);
    float v0 = xv.x, v1 = xv.y, v2 = xv.z, v3 = xv.w;

    float sum = v0 + v1 + v2 + v3;
#pragma unroll
    for (int o2 = 32; o2 > 0; o2 >>= 1) sum += __shfl_xor(sum, o2, 64);
    float mu = sum * (1.f / 256.f);

    float d0 = v0 - mu, d1 = v1 - mu, d2 = v2 - mu, d3 = v3 - mu;
    float ss = d0 * d0 + d1 * d1 + d2 * d2 + d3 * d3;
#pragma unroll
    for (int o2 = 32; o2 > 0; o2 >>= 1) ss += __shfl_xor(ss, o2, 64);
    float rstd = rsqrtf(ss * (1.f / 256.f) + 1e-5f);

    int c = lane * 4;
    float y0 = d0 * rstd * bf2f(s[c + 0]) + bf2f(b[c + 0]);
    float y1 = d1 * rstd * bf2f(s[c + 1]) + bf2f(b[c + 1]);
    float y2 = d2 * rstd * bf2f(s[c + 2]) + bf2f(b[c + 2]);
    float y3 = d3 * rstd * bf2f(s[c + 3]) + bf2f(b[c + 3]);

    *(float4*)(xf + off) = make_float4(y0, y1, y2, y3);
    if (is_final && *flag) {
        *(float4*)(f32_dst + off) = make_float4(y0, y1, y2, y3);
    } else {
        ushort4 uv;
        uv.x = f2bf(y0); uv.y = f2bf(y1); uv.z = f2bf(y2); uv.w = f2bf(y3);
        *(ushort4*)(xb_out + off) = uv;
    }
}

// ---------------------------------------------------------------------------
// Workspace: x_f32 39.58MB | U 59.38MB | Wbf 15.78MB | flag = ~114.8MB.
// x_b bf16 residual copy lives in d_out; final LN writes the real answer.
// ---------------------------------------------------------------------------
extern "C" void kernel_launch(void* const* d_in, const int* in_sizes, int n_in,
                              void* d_out, int out_size, void* d_ws, size_t ws_size,
                              hipStream_t stream)
{
    char* ws = (char*)d_ws;
    size_t o = 0;
    float*    x_f32 = (float*)(ws + o);    o += (size_t)M_ * D_ * 4;
    ushort_t* U     = (ushort_t*)(ws + o); o += (size_t)M_ * 768 * 2;
    ushort_t* Wbf   = (ushort_t*)(ws + o); o += (size_t)WTOT * 2;
    int*      flag  = (int*)(ws + o);      o += 256;
    ushort_t* x_b   = (ushort_t*)d_out;
    (void)ws_size; (void)in_sizes; (void)n_in; (void)out_size;

    detect_kernel<<<1, 256, 0, stream>>>((const unsigned int*)d_in[0], flag);

    WPtrs wp;
    for (int a = 0; a < 12; ++a) wp.p[a] = d_in[a + 1];
    cvt_all_kernel<<<(WTOT + 255) / 256, 256, 0, stream>>>(wp, flag, Wbf);

    const ushort_t* qkv_w = Wbf + 0;
    const ushort_t* qkv_b = Wbf + 1179648;
    const ushort_t* out_w = Wbf + 1184256;
    const ushort_t* out_b = Wbf + 1577472;
    const ushort_t* ff1_w = Wbf + 1579008;
    const ushort_t* ff1_b = Wbf + 4724736;
    const ushort_t* ff2_w = Wbf + 4737024;
    const ushort_t* ff2_b = Wbf + 7882752;
    const ushort_t* ln1_s = Wbf + 7884288;
    const ushort_t* ln1_b = Wbf + 7885824;
    const ushort_t* ln2_s = Wbf + 7887360;
    const ushort_t* ln2_b = Wbf + 7888896;

    cvt_src_kernel<<<(M_ * D_) / 256, 256, 0, stream>>>(d_in[0], flag, x_f32, x_b);

    for (int i = 0; i < NL_; ++i) {
        // QKV projection -> U [M,768] bf16
        gemm_bt<<<dim3(6, M_ / 128), 256, 0, stream>>>(
            x_b, qkv_w + (size_t)i * 768 * D_, qkv_b + (size_t)i * 768, U,
            768, D_, D_, 0);
        // MFMA block-diagonal attention; ctx overwrites q columns of U
        attn_kernel<<<B_ * 5, 256, 0, stream>>>(U);
        // out projection: x_f32 += ctx @ out_w^T + out_b (residual fused)
        gemm_bt<<<dim3(2, M_ / 128), 256, 0, stream>>>(
            U, out_w + (size_t)i * D_ * D_, out_b + (size_t)i * D_, x_f32,
            256, D_, 768, 2);
        // x = LN1(x)
        ln_kernel<<<M_ / 4, 256, 0, stream>>>(
            x_f32, ln1_s + (size_t)i * D_, ln1_b + (size_t)i * D_,
            x_b, nullptr, flag, 0);
        // fused FFN: x_f32 += W2 @ relu(W1 @ x_b + b1) + b2
        ffn_kernel<<<M_ / 128, 512, 0, stream>>>(
            x_b, ff1_w + (size_t)i * FF_ * D_, ff1_b + (size_t)i * FF_,
            ff2_w + (size_t)i * D_ * FF_, ff2_b + (size_t)i * D_, x_f32);
        // x = LN2(x); final layer writes d_out in the right dtype
        ln_kernel<<<M_ / 4, 256, 0, stream>>>(
            x_f32, ln2_s + (size_t)i * D_, ln2_b + (size_t)i * D_,
            x_b, (float*)d_out, flag, (i == NL_ - 1) ? 1 : 0);
    }
}

// Round 7
// 2453.088 us; speedup vs baseline: 1.3556x; 1.3556x over previous
//
#include <hip/hip_runtime.h>
#include <stdint.h>
#include <stddef.h>

#define B_ 256
#define L_ 151
#define D_ 256
#define H_ 8
#define DH_ 32
#define FF_ 2048
#define NL_ 6
#define M_ (B_ * L_)      // 38656 = 302 * 128

typedef unsigned short ushort_t;
typedef __bf16 bf16x8 __attribute__((ext_vector_type(8)));
typedef float f32x4 __attribute__((ext_vector_type(4)));
typedef unsigned short us8 __attribute__((ext_vector_type(8)));

__device__ __forceinline__ float bf2f(ushort_t u) {
    union { unsigned int i; float f; } v;
    v.i = ((unsigned int)u) << 16;
    return v.f;
}
__device__ __forceinline__ ushort_t f2bf(float f) {
    union { float f; unsigned int i; } v;
    v.f = f;
    unsigned int x = v.i;
    return (ushort_t)((x + 0x7fffu + ((x >> 16) & 1u)) >> 16);
}

__device__ __forceinline__ void gld_lds16(const ushort_t* g, ushort_t* l) {
    __builtin_amdgcn_global_load_lds(
        (const __attribute__((address_space(1))) void*)g,
        (__attribute__((address_space(3))) void*)l,
        16, 0, 0);
}

// ---------------------------------------------------------------------------
// Input dtype detection (flag: 0 = bf16 inputs, 1 = fp32 inputs).
// ---------------------------------------------------------------------------
__global__ __launch_bounds__(256)
void detect_kernel(const unsigned int* __restrict__ w, int* __restrict__ flag)
{
    __shared__ int sh[256];
    int tid = threadIdx.x;
    int cnt = 0;
    for (int i = tid; i < 1024; i += 256) {
        unsigned int x = w[i];
        int e = (x >> 7) & 0xFF;
        cnt += (e >= 110 && e <= 140) ? 1 : 0;
    }
    sh[tid] = cnt;
    __syncthreads();
    for (int s = 128; s > 0; s >>= 1) {
        if (tid < s) sh[tid] += sh[tid + s];
        __syncthreads();
    }
    if (tid == 0) *flag = (sh[0] > 512) ? 0 : 1;
}

// ---------------------------------------------------------------------------
// Convert ALL weights/biases to bf16 in one launch (compile-time segment map).
// ---------------------------------------------------------------------------
struct WPtrs { const void* p[12]; };

#define WTOT 7890432

__global__ __launch_bounds__(256)
void cvt_all_kernel(WPtrs w, const int* __restrict__ flag, ushort_t* __restrict__ out)
{
    size_t i = (size_t)blockIdx.x * 256 + threadIdx.x;
    if (i >= WTOT) return;
    int a; size_t base;
    if      (i < 1179648) { a = 0;  base = 0; }
    else if (i < 1184256) { a = 1;  base = 1179648; }
    else if (i < 1577472) { a = 2;  base = 1184256; }
    else if (i < 1579008) { a = 3;  base = 1577472; }
    else if (i < 4724736) { a = 4;  base = 1579008; }
    else if (i < 4737024) { a = 5;  base = 4724736; }
    else if (i < 7882752) { a = 6;  base = 4737024; }
    else if (i < 7884288) { a = 7;  base = 7882752; }
    else if (i < 7885824) { a = 8;  base = 7884288; }
    else if (i < 7887360) { a = 9;  base = 7885824; }
    else if (i < 7888896) { a = 10; base = 7887360; }
    else                  { a = 11; base = 7888896; }
    size_t j = i - base;
    if (*flag) out[i] = f2bf(((const float*)w.p[a])[j]);
    else       out[i] = ((const ushort_t*)w.p[a])[j];
}

// src -> fp32 residual stream + bf16 GEMM copy.
__global__ __launch_bounds__(256)
void cvt_src_kernel(const void* __restrict__ in, const int* __restrict__ flag,
                    float* __restrict__ xf, ushort_t* __restrict__ xb)
{
    size_t i = (size_t)blockIdx.x * 256 + threadIdx.x;
    float v = (*flag) ? ((const float*)in)[i] : bf2f(((const ushort_t*)in)[i]);
    xf[i] = v;
    xb[i] = f2bf(v);
}

// ---------------------------------------------------------------------------
// GEMM (m97): 128x128 tile, 4 waves, BK=64, global_load_lds staging.
// mode 0: bf16 store; mode 2: fp32 Out[i] += v (residual fusion).
// Used for QKV projection and attention out-projection (K=256).
// ---------------------------------------------------------------------------
__global__ __launch_bounds__(256, 2)
void gemm_bt(const ushort_t* __restrict__ A, const ushort_t* __restrict__ Bw,
             const ushort_t* __restrict__ bias, void* __restrict__ Out,
             int N, int K, int lda, int mode)
{
    alignas(16) __shared__ ushort_t lsA[128 * 64];
    alignas(16) __shared__ ushort_t lsB[128 * 64];

    const int tid  = threadIdx.x;
    const int wave = tid >> 6;
    const int lane = tid & 63;
    const int row0 = blockIdx.y * 128;
    const int col0 = blockIdx.x * 128;

    const int wr   = (wave >> 1) * 64;
    const int wc   = (wave & 1) * 64;
    const int lm   = lane & 15;
    const int quad = lane >> 4;

    f32x4 acc[4][4];
#pragma unroll
    for (int i = 0; i < 4; ++i)
#pragma unroll
        for (int j = 0; j < 4; ++j)
            acc[i][j] = (f32x4){0.f, 0.f, 0.f, 0.f};

    for (int k0 = 0; k0 < K; k0 += 64) {
        __syncthreads();
#pragma unroll
        for (int it = 0; it < 4; ++it) {
            int c16 = (it * 4 + wave) * 64 + lane;
            int r   = c16 >> 3;
            int kc  = c16 & 7;
            const ushort_t* ga = A  + (size_t)(row0 + r) * lda + k0 + kc * 8;
            const ushort_t* gb = Bw + (size_t)(col0 + r) * K   + k0 + kc * 8;
            gld_lds16(ga, &lsA[(size_t)(it * 4 + wave) * 512]);
            gld_lds16(gb, &lsB[(size_t)(it * 4 + wave) * 512]);
        }
        __syncthreads();

#pragma unroll
        for (int kc = 0; kc < 2; ++kc) {
            bf16x8 af[4], bfr[4];
#pragma unroll
            for (int i = 0; i < 4; ++i) {
                af[i]  = *reinterpret_cast<const bf16x8*>(
                             &lsA[(wr + i * 16 + lm) * 64 + kc * 32 + quad * 8]);
                bfr[i] = *reinterpret_cast<const bf16x8*>(
                             &lsB[(wc + i * 16 + lm) * 64 + kc * 32 + quad * 8]);
            }
#pragma unroll
            for (int i = 0; i < 4; ++i)
#pragma unroll
                for (int j = 0; j < 4; ++j)
                    acc[i][j] = __builtin_amdgcn_mfma_f32_16x16x32_bf16(
                        af[i], bfr[j], acc[i][j], 0, 0, 0);
        }
    }

    float bvals[4];
#pragma unroll
    for (int j = 0; j < 4; ++j)
        bvals[j] = bf2f(bias[col0 + wc + j * 16 + lm]);

#pragma unroll
    for (int i = 0; i < 4; ++i) {
        int mrow = row0 + wr + i * 16 + quad * 4;
#pragma unroll
        for (int j = 0; j < 4; ++j) {
            int ncol = col0 + wc + j * 16 + lm;
#pragma unroll
            for (int r = 0; r < 4; ++r) {
                float v = acc[i][j][r] + bvals[j];
                size_t idx = (size_t)(mrow + r) * N + ncol;
                if (mode == 2) {
                    ((float*)Out)[idx] += v;
                } else {
                    ((ushort_t*)Out)[idx] = f2bf(v);
                }
            }
        }
    }
}

// ---------------------------------------------------------------------------
// Fused FFN v2: x_f32[128-row strip] += W2 @ relu(W1 @ x + b1) + b2.
// 302 blocks x 512 thr (8 waves). h-chunk = 64, 32 chunks. Weights staged via
// global_load_lds into DOUBLE-BUFFERED LDS (prefetch c+1 before computing c;
// barriers drain the DMA — m97 implicit overlap). x A-frags preloaded ONCE
// into registers (64 VGPR). P round-trips LDS at stride 72 (2-way = free).
// v1 failed (403us, MfmaUtil 8%) because W frags were per-lane global loads.
// ---------------------------------------------------------------------------
__global__ __launch_bounds__(512)
void ffn_kernel(const ushort_t* __restrict__ xb, const ushort_t* __restrict__ W1,
                const ushort_t* __restrict__ b1, const ushort_t* __restrict__ W2,
                const ushort_t* __restrict__ b2, float* __restrict__ xf)
{
    alignas(16) __shared__ ushort_t W1c[2][64 * 256];   // 32 KB each
    alignas(16) __shared__ ushort_t W2c[2][256 * 64];   // 32 KB each
    alignas(16) __shared__ ushort_t Ps[128 * 72];       // 18 KB

    const int tid  = threadIdx.x;
    const int wave = tid >> 6;
    const int lane = tid & 63;
    const int lm   = lane & 15;
    const int quad = lane >> 4;
    const int row0 = blockIdx.x * 128;

    const int pr = (wave & 3) * 32;   // FF1: wave P-row base
    const int pc = (wave >> 2) * 32;  // FF1: wave P-col base (h-local)
    const int fr = (wave & 1) * 64;   // FF2: wave out-row base
    const int fc = (wave >> 1) * 64;  // FF2: wave out-col base

    // ---- preload x A-frags (rows pr..pr+31, full K=256) into registers ----
    bf16x8 xa[2][8];
#pragma unroll
    for (int i = 0; i < 2; ++i)
#pragma unroll
        for (int kk = 0; kk < 8; ++kk)
            xa[i][kk] = *(const bf16x8*)(xb + (size_t)(row0 + pr + i * 16 + lm) * 256
                                            + kk * 32 + quad * 8);

    f32x4 acc[4][4];
#pragma unroll
    for (int i = 0; i < 4; ++i)
#pragma unroll
        for (int j = 0; j < 4; ++j)
            acc[i][j] = (f32x4){0.f, 0.f, 0.f, 0.f};

    // ---- weight chunk staging: W1 rows [hb,hb+64) contiguous; W2 col-slice ----
    auto stageW = [&](int c, int buf) {
        const ushort_t* g1 = W1 + (size_t)c * 64 * 256;
#pragma unroll
        for (int t = 0; t < 4; ++t) {
            int idx = t * 512 + tid;                 // 16B chunk id, 0..2047
            gld_lds16(g1 + (size_t)idx * 8, &W1c[buf][(size_t)(t * 512 + wave * 64) * 8]);
        }
#pragma unroll
        for (int t = 0; t < 4; ++t) {
            int idx = t * 512 + tid;                 // row=idx>>3, k8=idx&7
            const ushort_t* g2 = W2 + (size_t)(idx >> 3) * 2048 + c * 64 + (idx & 7) * 8;
            gld_lds16(g2, &W2c[buf][(size_t)(t * 512 + wave * 64) * 8]);
        }
    };

    stageW(0, 0);
    __syncthreads();

    for (int c = 0; c < 32; ++c) {
        const int cur = c & 1;
        if (c + 1 < 32) stageW(c + 1, cur ^ 1);   // async prefetch

        // ---- FF1: p = x @ W1c^T for this wave's 32x32 P-tile ----
        f32x4 p[2][2];
#pragma unroll
        for (int i = 0; i < 2; ++i)
#pragma unroll
            for (int j = 0; j < 2; ++j)
                p[i][j] = (f32x4){0.f, 0.f, 0.f, 0.f};

#pragma unroll
        for (int kk = 0; kk < 8; ++kk) {
#pragma unroll
            for (int j = 0; j < 2; ++j) {
                bf16x8 wb = *(const bf16x8*)&W1c[cur][(pc + j * 16 + lm) * 256 + kk * 32 + quad * 8];
#pragma unroll
                for (int i = 0; i < 2; ++i)
                    p[i][j] = __builtin_amdgcn_mfma_f32_16x16x32_bf16(xa[i][kk], wb, p[i][j], 0, 0, 0);
            }
        }

        const int hb = c * 64;
#pragma unroll
        for (int j = 0; j < 2; ++j) {
            float bv = bf2f(b1[hb + pc + j * 16 + lm]);
#pragma unroll
            for (int i = 0; i < 2; ++i)
#pragma unroll
                for (int r = 0; r < 4; ++r)
                    Ps[(pr + i * 16 + quad * 4 + r) * 72 + pc + j * 16 + lm] =
                        f2bf(fmaxf(p[i][j][r] + bv, 0.f));
        }
        __syncthreads();   // P visible; prefetch DMA drained (issued ~1 phase ago)

        // ---- FF2: acc += P @ W2c^T ----
#pragma unroll
        for (int ks = 0; ks < 2; ++ks) {
            bf16x8 pa[4];
#pragma unroll
            for (int i = 0; i < 4; ++i)
                pa[i] = *(const bf16x8*)&Ps[(fr + i * 16 + lm) * 72 + ks * 32 + quad * 8];
#pragma unroll
            for (int j = 0; j < 4; ++j) {
                bf16x8 w2b = *(const bf16x8*)&W2c[cur][(fc + j * 16 + lm) * 64 + ks * 32 + quad * 8];
#pragma unroll
                for (int i = 0; i < 4; ++i)
                    acc[i][j] = __builtin_amdgcn_mfma_f32_16x16x32_bf16(pa[i], w2b, acc[i][j], 0, 0, 0);
            }
        }
        __syncthreads();   // Ps + W buf[cur] free for next iteration
    }

    // ---- epilogue: x_f32 += acc + b2 ----
    float b2v[4];
#pragma unroll
    for (int j = 0; j < 4; ++j)
        b2v[j] = bf2f(b2[fc + j * 16 + lm]);

#pragma unroll
    for (int i = 0; i < 4; ++i) {
        int mrow = row0 + fr + i * 16 + quad * 4;
#pragma unroll
        for (int j = 0; j < 4; ++j) {
            int ncol = fc + j * 16 + lm;
#pragma unroll
            for (int r = 0; r < 4; ++r)
                xf[(size_t)(mrow + r) * 256 + ncol] += acc[i][j][r] + b2v[j];
        }
    }
}

// ---------------------------------------------------------------------------
// MFMA block-diagonal attention, wave-per-head, zero block barriers.
// ---------------------------------------------------------------------------
__constant__ int c_starts[6] = {0, 50, 67, 84, 101, 151};

__global__ __launch_bounds__(256)
void attn_kernel(ushort_t* __restrict__ qkv)
{
    alignas(16) __shared__ ushort_t Vt[4][32 * 72];  // V^T: [dh][key]
    alignas(16) __shared__ ushort_t Pss[4][16 * 72]; // P strip: [row][key]

    const int b    = blockIdx.x / 5;
    const int blk  = blockIdx.x % 5;
    const int a0   = c_starts[blk];
    const int n    = c_starts[blk + 1] - a0;
    const int wave = threadIdx.x >> 6;
    const int lane = threadIdx.x & 63;
    const int lm   = lane & 15;
    const int quad = lane >> 4;
    const float scale = 0.17677669529663687f;  // 1/sqrt(32)

    const size_t rowbase = (size_t)b * L_ + a0;

    for (int hi = 0; hi < 2; ++hi) {
        const int h = wave + hi * 4;
        const int hoff = h * 32;

#pragma unroll
        for (int it = 0; it < 4; ++it) {
            int gidx = it * 64 + lane;
            int c    = gidx >> 2;
            int dcc  = (gidx & 3) * 8;
            us8 v = *(const us8*)(qkv + (rowbase + c) * 768 + 512 + hoff + dcc);
            if (c >= n) v = (us8){0,0,0,0,0,0,0,0};
#pragma unroll
            for (int j = 0; j < 8; ++j)
                Vt[wave][(dcc + j) * 72 + c] = v[j];
        }

        bf16x8 kb[4];
#pragma unroll
        for (int j = 0; j < 4; ++j)
            kb[j] = *(const bf16x8*)(qkv + (rowbase + 16 * j + lm) * 768 + 256 + hoff + quad * 8);

        bf16x8 vb[2][2];
#pragma unroll
        for (int t = 0; t < 2; ++t)
#pragma unroll
            for (int kc = 0; kc < 2; ++kc)
                vb[t][kc] = *(const bf16x8*)&Vt[wave][(16 * t + lm) * 72 + kc * 32 + quad * 8];

        for (int i = 0; i < 4 && 16 * i < n; ++i) {
            bf16x8 qa = *(const bf16x8*)(qkv + (rowbase + 16 * i + lm) * 768 + hoff + quad * 8);

            f32x4 s[4];
#pragma unroll
            for (int j = 0; j < 4; ++j)
                s[j] = __builtin_amdgcn_mfma_f32_16x16x32_bf16(
                    qa, kb[j], (f32x4){0.f, 0.f, 0.f, 0.f}, 0, 0, 0);

#pragma unroll
            for (int j = 0; j < 4; ++j) {
                bool valid = (16 * j + lm) < n;
#pragma unroll
                for (int r = 0; r < 4; ++r)
                    s[j][r] = valid ? s[j][r] * scale : -1e30f;
            }

            float inv[4];
#pragma unroll
            for (int r = 0; r < 4; ++r) {
                float mx = fmaxf(fmaxf(s[0][r], s[1][r]), fmaxf(s[2][r], s[3][r]));
#pragma unroll
                for (int o2 = 1; o2 < 16; o2 <<= 1) mx = fmaxf(mx, __shfl_xor(mx, o2, 64));
                float sum = 0.f;
#pragma unroll
                for (int j = 0; j < 4; ++j) {
                    float ev = __expf(s[j][r] - mx);
                    s[j][r] = ev;
                    sum += ev;
                }
#pragma unroll
                for (int o2 = 1; o2 < 16; o2 <<= 1) sum += __shfl_xor(sum, o2, 64);
                inv[r] = 1.0f / sum;
            }

#pragma unroll
            for (int j = 0; j < 4; ++j)
#pragma unroll
                for (int r = 0; r < 4; ++r)
                    Pss[wave][(quad * 4 + r) * 72 + 16 * j + lm] = f2bf(s[j][r]);

            bf16x8 pa0 = *(const bf16x8*)&Pss[wave][lm * 72 + quad * 8];
            bf16x8 pa1 = *(const bf16x8*)&Pss[wave][lm * 72 + 32 + quad * 8];

            f32x4 o[2];
#pragma unroll
            for (int t = 0; t < 2; ++t) {
                o[t] = __builtin_amdgcn_mfma_f32_16x16x32_bf16(
                    pa0, vb[t][0], (f32x4){0.f, 0.f, 0.f, 0.f}, 0, 0, 0);
                o[t] = __builtin_amdgcn_mfma_f32_16x16x32_bf16(
                    pa1, vb[t][1], o[t], 0, 0, 0);
            }

#pragma unroll
            for (int r = 0; r < 4; ++r) {
                int m = 16 * i + quad * 4 + r;
                if (m < n) {
#pragma unroll
                    for (int t = 0; t < 2; ++t)
                        qkv[(rowbase + m) * 768 + hoff + 16 * t + lm] =
                            f2bf(o[t][r] * inv[r]);
                }
            }
        }
    }
}

// ---------------------------------------------------------------------------
// LayerNorm over pre-summed x_f32 (residual adds fused into producers).
// ---------------------------------------------------------------------------
__global__ __launch_bounds__(256)
void ln_kernel(float* __restrict__ xf, const ushort_t* __restrict__ s,
               const ushort_t* __restrict__ b, ushort_t* __restrict__ xb_out,
               float* __restrict__ f32_dst, const int* __restrict__ flag,
               int is_final)
{
    const int wave = threadIdx.x >> 6;
    const int lane = threadIdx.x & 63;
    const int row  = blockIdx.x * 4 + wave;
    const size_t off = (size_t)row * D_ + lane * 4;

    float4 xv = *(const float4*)(xf + off);
    float v0 = xv.x, v1 = xv.y, v2 = xv.z, v3 = xv.w;

    float sum = v0 + v1 + v2 + v3;
#pragma unroll
    for (int o2 = 32; o2 > 0; o2 >>= 1) sum += __shfl_xor(sum, o2, 64);
    float mu = sum * (1.f / 256.f);

    float d0 = v0 - mu, d1 = v1 - mu, d2 = v2 - mu, d3 = v3 - mu;
    float ss = d0 * d0 + d1 * d1 + d2 * d2 + d3 * d3;
#pragma unroll
    for (int o2 = 32; o2 > 0; o2 >>= 1) ss += __shfl_xor(ss, o2, 64);
    float rstd = rsqrtf(ss * (1.f / 256.f) + 1e-5f);

    int c = lane * 4;
    float y0 = d0 * rstd * bf2f(s[c + 0]) + bf2f(b[c + 0]);
    float y1 = d1 * rstd * bf2f(s[c + 1]) + bf2f(b[c + 1]);
    float y2 = d2 * rstd * bf2f(s[c + 2]) + bf2f(b[c + 2]);
    float y3 = d3 * rstd * bf2f(s[c + 3]) + bf2f(b[c + 3]);

    *(float4*)(xf + off) = make_float4(y0, y1, y2, y3);
    if (is_final && *flag) {
        *(float4*)(f32_dst + off) = make_float4(y0, y1, y2, y3);
    } else {
        ushort4 uv;
        uv.x = f2bf(y0); uv.y = f2bf(y1); uv.z = f2bf(y2); uv.w = f2bf(y3);
        *(ushort4*)(xb_out + off) = uv;
    }
}

// ---------------------------------------------------------------------------
// Workspace: x_f32 39.58MB | U 59.38MB | Wbf 15.78MB | flag = ~114.8MB.
// x_b bf16 residual copy lives in d_out; final LN writes the real answer.
// ---------------------------------------------------------------------------
extern "C" void kernel_launch(void* const* d_in, const int* in_sizes, int n_in,
                              void* d_out, int out_size, void* d_ws, size_t ws_size,
                              hipStream_t stream)
{
    char* ws = (char*)d_ws;
    size_t o = 0;
    float*    x_f32 = (float*)(ws + o);    o += (size_t)M_ * D_ * 4;
    ushort_t* U     = (ushort_t*)(ws + o); o += (size_t)M_ * 768 * 2;
    ushort_t* Wbf   = (ushort_t*)(ws + o); o += (size_t)WTOT * 2;
    int*      flag  = (int*)(ws + o);      o += 256;
    ushort_t* x_b   = (ushort_t*)d_out;
    (void)ws_size; (void)in_sizes; (void)n_in; (void)out_size;

    detect_kernel<<<1, 256, 0, stream>>>((const unsigned int*)d_in[0], flag);

    WPtrs wp;
    for (int a = 0; a < 12; ++a) wp.p[a] = d_in[a + 1];
    cvt_all_kernel<<<(WTOT + 255) / 256, 256, 0, stream>>>(wp, flag, Wbf);

    const ushort_t* qkv_w = Wbf + 0;
    const ushort_t* qkv_b = Wbf + 1179648;
    const ushort_t* out_w = Wbf + 1184256;
    const ushort_t* out_b = Wbf + 1577472;
    const ushort_t* ff1_w = Wbf + 1579008;
    const ushort_t* ff1_b = Wbf + 4724736;
    const ushort_t* ff2_w = Wbf + 4737024;
    const ushort_t* ff2_b = Wbf + 7882752;
    const ushort_t* ln1_s = Wbf + 7884288;
    const ushort_t* ln1_b = Wbf + 7885824;
    const ushort_t* ln2_s = Wbf + 7887360;
    const ushort_t* ln2_b = Wbf + 7888896;

    cvt_src_kernel<<<(M_ * D_) / 256, 256, 0, stream>>>(d_in[0], flag, x_f32, x_b);

    for (int i = 0; i < NL_; ++i) {
        // QKV projection -> U [M,768] bf16
        gemm_bt<<<dim3(6, M_ / 128), 256, 0, stream>>>(
            x_b, qkv_w + (size_t)i * 768 * D_, qkv_b + (size_t)i * 768, U,
            768, D_, D_, 0);
        // MFMA block-diagonal attention; ctx overwrites q columns of U
        attn_kernel<<<B_ * 5, 256, 0, stream>>>(U);
        // out projection: x_f32 += ctx @ out_w^T + out_b (residual fused)
        gemm_bt<<<dim3(2, M_ / 128), 256, 0, stream>>>(
            U, out_w + (size_t)i * D_ * D_, out_b + (size_t)i * D_, x_f32,
            256, D_, 768, 2);
        // x = LN1(x)
        ln_kernel<<<M_ / 4, 256, 0, stream>>>(
            x_f32, ln1_s + (size_t)i * D_, ln1_b + (size_t)i * D_,
            x_b, nullptr, flag, 0);
        // fused FFN v2: x_f32 += W2 @ relu(W1 @ x_b + b1) + b2
        ffn_kernel<<<M_ / 128, 512, 0, stream>>>(
            x_b, ff1_w + (size_t)i * FF_ * D_, ff1_b + (size_t)i * FF_,
            ff2_w + (size_t)i * D_ * FF_, ff2_b + (size_t)i * D_, x_f32);
        // x = LN2(x); final layer writes d_out in the right dtype
        ln_kernel<<<M_ / 4, 256, 0, stream>>>(
            x_f32, ln2_s + (size_t)i * D_, ln2_b + (size_t)i * D_,
            x_b, (float*)d_out, flag, (i == NL_ - 1) ? 1 : 0);
    }
}